// Round 2
// baseline (159.735 us; speedup 1.0000x reference)
//
#include <hip/hip_runtime.h>
#include <hip/hip_bf16.h>

#define BB 32
#define SS 64
#define WW 30
#define EE 300
#define VDD 128
#define HH 32

typedef short bf16x8 __attribute__((ext_vector_type(8)));
typedef float f32x4 __attribute__((ext_vector_type(4)));

__device__ __forceinline__ ushort f2bf(float f) {
  union { float f; unsigned u; } x; x.f = f;
  unsigned r = x.u + 0x7fffu + ((x.u >> 16) & 1u);
  return (ushort)(r >> 16);
}
__device__ __forceinline__ float bf2f(ushort u) {
  union { unsigned u; float f; } x; x.u = ((unsigned)u) << 16; return x.f;
}

// ---- kernel 1: Q = voice@W1+b1 ; A = softmax(Q Q^T - keymask) ----
__global__ __launch_bounds__(256) void k_qk(
    const float* __restrict__ voice, const int* __restrict__ sent,
    const float* __restrict__ W1, const float* __restrict__ b1,
    float* __restrict__ Aout) {
  __shared__ float sv[SS][VDD];
  __shared__ float sw[VDD][HH];
  __shared__ float sb1[HH];
  __shared__ float sq[SS][HH];
  __shared__ float sa[SS][SS];
  int b = blockIdx.x, t = threadIdx.x;
  const float4* vsrc = (const float4*)(voice + (size_t)b * SS * VDD);
  float4* vdst = (float4*)&sv[0][0];
  for (int i = t; i < SS * VDD / 4; i += 256) vdst[i] = vsrc[i];
  const float4* wsrc = (const float4*)W1;
  float4* wdst = (float4*)&sw[0][0];
  for (int i = t; i < VDD * HH / 4; i += 256) wdst[i] = wsrc[i];
  if (t < HH) sb1[t] = b1[t];
  __syncthreads();
  for (int o = t; o < SS * HH; o += 256) {
    int s = o >> 5, j = o & 31;
    float acc = sb1[j];
    #pragma unroll 4
    for (int d = 0; d < VDD; ++d) acc += sv[s][d] * sw[d][j];
    sq[s][j] = acc;
  }
  __syncthreads();
  int sn = sent[b];
  for (int o = t; o < SS * SS; o += 256) {
    int q = o >> 6, k = o & 63;
    float acc = 0.f;
    #pragma unroll 8
    for (int j = 0; j < HH; ++j) acc += sq[q][j] * sq[k][j];
    if (k >= sn) acc -= 1e12f;
    sa[q][k] = acc;
  }
  __syncthreads();
  int wv = t >> 6, ln = t & 63;
  for (int q = wv; q < SS; q += 4) {
    float v = sa[q][ln];
    float mx = v;
    #pragma unroll
    for (int off = 32; off; off >>= 1) mx = fmaxf(mx, __shfl_xor(mx, off));
    float e = expf(v - mx);
    float sm = e;
    #pragma unroll
    for (int off = 32; off; off >>= 1) sm += __shfl_xor(sm, off);
    Aout[((size_t)b * SS + q) * SS + ln] = e / sm;
  }
}

// ---- kernel 2: gather word embeddings -> bf16 rows [61440][300] ----
__global__ void k_gather(const int* __restrict__ widx, const float* __restrict__ emb,
                         ushort* __restrict__ web) {
  int tid = blockIdx.x * 256 + threadIdx.x;
  if (tid >= BB * SS * WW * 75) return;
  int row = tid / 75, p = tid - row * 75;
  int idx = widx[row];
  float4 v = *(const float4*)(emb + (size_t)idx * EE + p * 4);
  ushort4 o;
  o.x = f2bf(v.x); o.y = f2bf(v.y); o.z = f2bf(v.z); o.w = f2bf(v.w);
  *(ushort4*)(web + (size_t)row * EE + p * 4) = o;
}

// ---- kernel 3: W2 -> transposed, K-padded bf16 [304][640] ----
// k' in [0,320): c = k' (valid < 300); k' in [320,640): c = k'-20 (valid < 620)
__global__ void k_w2t(const float* __restrict__ W2, ushort* __restrict__ w2t) {
  int o = blockIdx.x * 256 + threadIdx.x;
  if (o >= 304 * 640) return;
  int e = o / 640, cp = o - e * 640;
  int c = cp < 320 ? cp : cp - 20;
  float v = 0.f;
  if (e < EE && (cp < 320 ? cp < 300 : cp < 620)) v = W2[c * EE + e];
  w2t[o] = f2bf(v);
}

// ---- kernel 4: Obf = mask .* (A @ V) in bf16, rows [61440][300] ----
__global__ __launch_bounds__(256) void k_pv(
    const float* __restrict__ Aout, const ushort* __restrict__ web,
    const int* __restrict__ sent, ushort* __restrict__ obf) {
  __shared__ float svv[SS][128];
  __shared__ float sa[SS][SS];
  int nc = blockIdx.x, b = blockIdx.y, t = threadIdx.x;
  int n0 = nc * 128;
  const float4* as = (const float4*)(Aout + (size_t)b * SS * SS);
  float4* ad = (float4*)&sa[0][0];
  for (int i = t; i < SS * SS / 4; i += 256) ad[i] = as[i];
  for (int g = t; g < SS * 32; g += 256) {
    int k = g >> 5, c4 = (g & 31) << 2;
    int n = n0 + c4;
    float4 vf = {0.f, 0.f, 0.f, 0.f};
    if (n + 3 < 9000) {
      ushort4 u = *(const ushort4*)(web + ((size_t)(b * SS + k)) * 9000 + n);
      vf.x = bf2f(u.x); vf.y = bf2f(u.y); vf.z = bf2f(u.z); vf.w = bf2f(u.w);
    }
    *(float4*)&svv[k][c4] = vf;
  }
  __syncthreads();
  int sn = sent[b];
  int qb = (t >> 5) << 3;    // 8 q's per thread
  int nt = (t & 31) << 2;    // 4 n's per thread
  float acc[8][4];
  #pragma unroll
  for (int j = 0; j < 8; ++j)
    #pragma unroll
    for (int x = 0; x < 4; ++x) acc[j][x] = 0.f;
  if (qb < sn) {
    for (int k = 0; k < sn; ++k) {
      float4 v = *(const float4*)&svv[k][nt];
      #pragma unroll
      for (int j = 0; j < 8; ++j) {
        float a = sa[qb + j][k];
        acc[j][0] += a * v.x; acc[j][1] += a * v.y;
        acc[j][2] += a * v.z; acc[j][3] += a * v.w;
      }
    }
  }
  if (n0 + nt + 3 < 9000) {
    #pragma unroll
    for (int j = 0; j < 8; ++j) {
      int q = qb + j;
      bool live = q < sn;
      ushort4 o;
      o.x = f2bf(live ? acc[j][0] : 0.f);
      o.y = f2bf(live ? acc[j][1] : 0.f);
      o.z = f2bf(live ? acc[j][2] : 0.f);
      o.w = f2bf(live ? acc[j][3] : 0.f);
      *(ushort4*)(obf + ((size_t)(b * SS + q)) * 9000 + n0 + nt) = o;
    }
  }
}

// ---- kernel 5: out[b,e,s,w] = (concat @ W2 + b2), computed transposed ----
// D[e][r] = sum_k W2t[e][k] * concat[r][k]; A-op = W2t (global), B-op = concat tile (LDS)
__global__ __launch_bounds__(256) void k_out(
    const ushort* __restrict__ obf, const ushort* __restrict__ web,
    const ushort* __restrict__ w2t, const float* __restrict__ b2,
    float* __restrict__ out) {
  __shared__ ushort sb[64][72];   // +8 pad: breaks 128B-stride bank conflict
  __shared__ float sb2[304];
  int blk = blockIdx.x, t = threadIdx.x;
  int wv = t >> 6, ln = t & 63;
  size_t r0 = (size_t)blk * 64;
  int bbat = blk / 30;            // 1920 rows per batch, 64 | 1920
  int rin0 = (blk % 30) * 64;
  for (int i = t; i < 304; i += 256) sb2[i] = (i < 300) ? b2[i] : 0.f;  // FIX: cover all 304
  f32x4 acc[5][4];
  #pragma unroll
  for (int i = 0; i < 5; ++i)
    #pragma unroll
    for (int nf = 0; nf < 4; ++nf) acc[i][nf] = (f32x4){0.f, 0.f, 0.f, 0.f};
  int rr = t >> 2, c0 = (t & 3) << 4;
  int lr = ln & 15, lg = ln >> 4;
  for (int kc = 0; kc < 10; ++kc) {
    const ushort* src = (kc < 5) ? obf : web;
    int cbase = (kc < 5 ? kc : kc - 5) * 64 + c0;
    const ushort* s = src + (r0 + rr) * 300 + cbase;
    if (cbase + 15 < 300) {
      uint2 a0 = *(const uint2*)(s);
      uint2 a1 = *(const uint2*)(s + 4);
      uint2 a2 = *(const uint2*)(s + 8);
      uint2 a3 = *(const uint2*)(s + 12);
      *(uint2*)&sb[rr][c0]      = a0;
      *(uint2*)&sb[rr][c0 + 4]  = a1;
      *(uint2*)&sb[rr][c0 + 8]  = a2;
      *(uint2*)&sb[rr][c0 + 12] = a3;
    } else {
      #pragma unroll
      for (int ii = 0; ii < 16; ++ii)
        sb[rr][c0 + ii] = (cbase + ii < 300) ? s[ii] : (ushort)0;
    }
    __syncthreads();
    bf16x8 bfr[4][2];
    #pragma unroll
    for (int nf = 0; nf < 4; ++nf)
      #pragma unroll
      for (int ks = 0; ks < 2; ++ks)
        bfr[nf][ks] = *(const bf16x8*)&sb[nf * 16 + lr][ks * 32 + lg * 8];
    #pragma unroll
    for (int i = 0; i < 5; ++i) {
      int ms = wv + 4 * i;
      if (ms < 19) {
        #pragma unroll
        for (int ks = 0; ks < 2; ++ks) {
          bf16x8 afr = *(const bf16x8*)(w2t +
              (size_t)(ms * 16 + lr) * 640 + kc * 64 + ks * 32 + lg * 8);
          #pragma unroll
          for (int nf = 0; nf < 4; ++nf)
            acc[i][nf] = __builtin_amdgcn_mfma_f32_16x16x32_bf16(
                afr, bfr[nf][ks], acc[i][nf], 0, 0, 0);
        }
      }
    }
    __syncthreads();
  }
  #pragma unroll
  for (int i = 0; i < 5; ++i) {
    int ms = wv + 4 * i;
    if (ms >= 19) continue;
    #pragma unroll
    for (int nf = 0; nf < 4; ++nf) {
      int rin = rin0 + nf * 16 + lr;
      #pragma unroll
      for (int j = 0; j < 4; ++j) {
        int e = ms * 16 + lg * 4 + j;
        if (e < 300)
          out[(size_t)(bbat * 300 + e) * 1920 + rin] = acc[i][nf][j] + sb2[e];
      }
    }
  }
}

extern "C" void kernel_launch(void* const* d_in, const int* in_sizes, int n_in,
                              void* d_out, int out_size, void* d_ws, size_t ws_size,
                              hipStream_t stream) {
  const int*   widx  = (const int*)d_in[0];
  const float* voice = (const float*)d_in[1];
  const int*   sent  = (const int*)d_in[2];
  const float* emb   = (const float*)d_in[4];
  const float* W1    = (const float*)d_in[5];
  const float* b1    = (const float*)d_in[6];
  const float* W2    = (const float*)d_in[7];
  const float* b2    = (const float*)d_in[8];
  float* out  = (float*)d_out;
  float* Aout = out + (size_t)BB * EE * SS * WW;  // O first, then A

  ushort* web = (ushort*)d_ws;                    // [61440][300] bf16
  ushort* obf = web + (size_t)18432000;           // [61440][300] bf16
  ushort* w2t = obf + (size_t)18432000;           // [304][640] bf16

  hipLaunchKernelGGL(k_qk, dim3(BB), dim3(256), 0, stream, voice, sent, W1, b1, Aout);
  hipLaunchKernelGGL(k_gather, dim3((BB * SS * WW * 75 + 255) / 256), dim3(256), 0, stream,
                     widx, emb, web);
  hipLaunchKernelGGL(k_w2t, dim3((304 * 640 + 255) / 256), dim3(256), 0, stream, W2, w2t);
  hipLaunchKernelGGL(k_pv, dim3(71, BB), dim3(256), 0, stream, Aout, web, sent, obf);
  hipLaunchKernelGGL(k_out, dim3(960), dim3(256), 0, stream, obf, web, w2t, b2, out);
}

// Round 3
// 143.622 us; speedup vs baseline: 1.1122x; 1.1122x over previous
//
#include <hip/hip_runtime.h>

#define BB 32
#define SS 64
#define WW 30
#define EE 300
#define VDD 128
#define HH 32

typedef short bf16x8 __attribute__((ext_vector_type(8)));
typedef float f32x4 __attribute__((ext_vector_type(4)));

__device__ __forceinline__ ushort f2bf(float f) {
  union { float f; unsigned u; } x; x.f = f;
  unsigned r = x.u + 0x7fffu + ((x.u >> 16) & 1u);
  return (ushort)(r >> 16);
}
__device__ __forceinline__ float bf2f(ushort u) {
  union { unsigned u; float f; } x; x.u = ((unsigned)u) << 16; return x.f;
}

// ---- K1: fused [qk (blocks 0..31)] [w2tp pack (32..126)] [gather (127..18126)] ----
__global__ __launch_bounds__(256) void k_front(
    const float* __restrict__ voice, const int* __restrict__ sent,
    const float* __restrict__ W1, const float* __restrict__ b1,
    const int* __restrict__ widx, const float* __restrict__ emb,
    const float* __restrict__ W2,
    float* __restrict__ Aout, ushort* __restrict__ web, ushort* __restrict__ w2tp) {
  __shared__ float sq[SS][33];   // +1 pad: row-stride 33 words -> conflict-free column reads
  int blk = blockIdx.x, t = threadIdx.x;
  if (blk < 32) {
    // ---- qk: Q = voice@W1+b1 ; A = softmax(QQ^T - keymask) ----
    int b = blk;
    for (int o = t; o < SS * HH; o += 256) {
      int s = o >> 5, j = o & 31;
      const float* vrow = voice + ((size_t)b * SS + s) * VDD;
      float acc = b1[j];
      #pragma unroll 8
      for (int d = 0; d < VDD; ++d) acc += vrow[d] * W1[d * HH + j];
      sq[s][j] = acc;
    }
    __syncthreads();
    int sn = sent[b];
    int wv = t >> 6, ln = t & 63;
    for (int q = wv; q < SS; q += 4) {
      float acc = 0.f;
      #pragma unroll
      for (int j = 0; j < HH; ++j) acc += sq[q][j] * sq[ln][j];
      if (ln >= sn) acc -= 1e12f;
      float mx = acc;
      #pragma unroll
      for (int off = 32; off; off >>= 1) mx = fmaxf(mx, __shfl_xor(mx, off));
      float e = expf(acc - mx);
      float sm = e;
      #pragma unroll
      for (int off = 32; off; off >>= 1) sm += __shfl_xor(sm, off);
      Aout[((size_t)b * SS + q) * SS + ln] = e / sm;
    }
  } else if (blk < 127) {
    // ---- w2tp pack: fragment-major A-operand. tile tI=(kc*2+ks)*19+ms, 64 lanes, 8 bf16 ----
    int g = (blk - 32) * 256 + t;
    if (g < 380 * 64) {
      int tI = g >> 6, lane = g & 63;
      int kc2 = tI / 19, ms = tI - kc2 * 19;
      int kc = kc2 >> 1, ks = kc2 & 1;
      int lg = lane >> 4, lr = lane & 15;
      int e = ms * 16 + lr;
      int kp0 = kc * 64 + ks * 32 + lg * 8;
      ushort v[8];
      #pragma unroll
      for (int j = 0; j < 8; ++j) {
        int kp = kp0 + j;
        int c = kp < 320 ? kp : kp - 20;
        bool ok = (e < EE) && (kp < 320 ? kp < 300 : kp < 620);
        v[j] = ok ? f2bf(W2[(size_t)c * EE + e]) : (ushort)0;
      }
      ushort* dst = w2tp + (size_t)g * 8;
      *(ushort4*)dst = *(ushort4*)&v[0];
      *(ushort4*)(dst + 4) = *(ushort4*)&v[4];
    }
  } else {
    // ---- gather: emb rows -> bf16 [61440][300] ----
    int tid = (blk - 127) * 256 + t;
    if (tid < BB * SS * WW * 75) {
      int row = tid / 75, p = tid - row * 75;
      int idx = widx[row];
      float4 v = *(const float4*)(emb + (size_t)idx * EE + p * 4);
      ushort4 o;
      o.x = f2bf(v.x); o.y = f2bf(v.y); o.z = f2bf(v.z); o.w = f2bf(v.w);
      *(ushort4*)(web + (size_t)row * EE + p * 4) = o;
    }
  }
}

// ---- K2: Obf = mask .* (A @ V) in bf16, rows [61440][300] ----
__global__ __launch_bounds__(256) void k_pv(
    const float* __restrict__ Aout, const ushort* __restrict__ web,
    const int* __restrict__ sent, ushort* __restrict__ obf) {
  __shared__ float svv[SS][128];
  __shared__ float sa[SS][SS];
  int nc = blockIdx.x, b = blockIdx.y, t = threadIdx.x;
  int n0 = nc * 128;
  const float4* as = (const float4*)(Aout + (size_t)b * SS * SS);
  float4* ad = (float4*)&sa[0][0];
  for (int i = t; i < SS * SS / 4; i += 256) ad[i] = as[i];
  for (int g = t; g < SS * 32; g += 256) {
    int k = g >> 5, c4 = (g & 31) << 2;
    int n = n0 + c4;
    float4 vf = {0.f, 0.f, 0.f, 0.f};
    if (n + 3 < 9000) {
      ushort4 u = *(const ushort4*)(web + ((size_t)(b * SS + k)) * 9000 + n);
      vf.x = bf2f(u.x); vf.y = bf2f(u.y); vf.z = bf2f(u.z); vf.w = bf2f(u.w);
    }
    *(float4*)&svv[k][c4] = vf;
  }
  __syncthreads();
  int sn = sent[b];
  int qb = (t >> 5) << 3;
  int nt = (t & 31) << 2;
  float acc[8][4];
  #pragma unroll
  for (int j = 0; j < 8; ++j)
    #pragma unroll
    for (int x = 0; x < 4; ++x) acc[j][x] = 0.f;
  if (qb < sn) {
    for (int k = 0; k < sn; ++k) {
      float4 v = *(const float4*)&svv[k][nt];
      #pragma unroll
      for (int j = 0; j < 8; ++j) {
        float a = sa[qb + j][k];
        acc[j][0] += a * v.x; acc[j][1] += a * v.y;
        acc[j][2] += a * v.z; acc[j][3] += a * v.w;
      }
    }
  }
  if (n0 + nt + 3 < 9000) {
    #pragma unroll
    for (int j = 0; j < 8; ++j) {
      int q = qb + j;
      bool live = q < sn;
      ushort4 o;
      o.x = f2bf(live ? acc[j][0] : 0.f);
      o.y = f2bf(live ? acc[j][1] : 0.f);
      o.z = f2bf(live ? acc[j][2] : 0.f);
      o.w = f2bf(live ? acc[j][3] : 0.f);
      *(ushort4*)(obf + ((size_t)(b * SS + q)) * 9000 + n0 + nt) = o;
    }
  }
}

// ---- K3: out = (concat @ W2 + b2) computed transposed, pipelined ----
__global__ __launch_bounds__(256, 4) void k_out2(
    const ushort* __restrict__ obf, const ushort* __restrict__ web,
    const ushort* __restrict__ w2tp, const float* __restrict__ b2,
    float* __restrict__ out) {
  __shared__ ushort sb[2][64][72];
  __shared__ float sb2[304];
  int blk = blockIdx.x, t = threadIdx.x;
  int wv = t >> 6, ln = t & 63;
  size_t r0 = (size_t)blk * 64;
  int bbat = blk / 30;
  int rin0 = (blk % 30) * 64;
  for (int i = t; i < 304; i += 256) sb2[i] = (i < 300) ? b2[i] : 0.f;
  f32x4 acc[5][4];
  #pragma unroll
  for (int i = 0; i < 5; ++i)
    #pragma unroll
    for (int nf = 0; nf < 4; ++nf) acc[i][nf] = (f32x4){0.f, 0.f, 0.f, 0.f};
  int rr = t >> 2, c0 = (t & 3) << 4;
  int lr = ln & 15, lg = ln >> 4;

  uint2 pr[4];
  auto LOADK = [&](int kc) {
    const ushort* src = (kc < 5) ? obf : web;
    int cb = (kc < 5 ? kc : kc - 5) * 64 + c0;
    const ushort* s = src + (r0 + rr) * 300 + cb;
    pr[0] = *(const uint2*)(s);
    pr[1] = *(const uint2*)(s + 4);
    pr[2] = *(const uint2*)(s + 8);
    pr[3] = *(const uint2*)(s + 12);
  };
  auto WRITEK = [&](int kc, int buf) {
    int cb = (kc < 5 ? kc : kc - 5) * 64 + c0;
    if (cb + 15 < 300) {
      *(uint2*)&sb[buf][rr][c0]      = pr[0];
      *(uint2*)&sb[buf][rr][c0 + 4]  = pr[1];
      *(uint2*)&sb[buf][rr][c0 + 8]  = pr[2];
      *(uint2*)&sb[buf][rr][c0 + 12] = pr[3];
    } else {
      union { uint2 u[4]; ushort s[16]; } tmp;
      tmp.u[0] = pr[0]; tmp.u[1] = pr[1]; tmp.u[2] = pr[2]; tmp.u[3] = pr[3];
      #pragma unroll
      for (int ii = 0; ii < 16; ++ii)
        sb[buf][rr][c0 + ii] = (cb + ii < 300) ? tmp.s[ii] : (ushort)0;
    }
  };

  LOADK(0);
  WRITEK(0, 0);
  __syncthreads();
  for (int kc = 0; kc < 10; ++kc) {
    int cur = kc & 1;
    if (kc < 9) LOADK(kc + 1);          // prefetch next K-tile into regs
    bf16x8 bfr[4][2];
    #pragma unroll
    for (int nf = 0; nf < 4; ++nf)
      #pragma unroll
      for (int ks = 0; ks < 2; ++ks)
        bfr[nf][ks] = *(const bf16x8*)&sb[cur][nf * 16 + lr][ks * 32 + lg * 8];
    #pragma unroll
    for (int i = 0; i < 5; ++i) {
      int ms = wv + 4 * i;
      if (ms < 19) {
        #pragma unroll
        for (int ks = 0; ks < 2; ++ks) {
          // fragment-major: one fully-coalesced 1024B load per wave
          bf16x8 afr = *(const bf16x8*)(w2tp +
              ((size_t)((kc * 2 + ks) * 19 + ms) * 64 + ln) * 8);
          #pragma unroll
          for (int nf = 0; nf < 4; ++nf)
            acc[i][nf] = __builtin_amdgcn_mfma_f32_16x16x32_bf16(
                afr, bfr[nf][ks], acc[i][nf], 0, 0, 0);
        }
      }
    }
    if (kc < 9) WRITEK(kc + 1, cur ^ 1);
    __syncthreads();
  }
  #pragma unroll
  for (int i = 0; i < 5; ++i) {
    int ms = wv + 4 * i;
    if (ms >= 19) continue;
    #pragma unroll
    for (int nf = 0; nf < 4; ++nf) {
      int rin = rin0 + nf * 16 + lr;
      #pragma unroll
      for (int j = 0; j < 4; ++j) {
        int e = ms * 16 + lg * 4 + j;
        if (e < 300)
          out[(size_t)(bbat * 300 + e) * 1920 + rin] = acc[i][nf][j] + sb2[e];
      }
    }
  }
}

extern "C" void kernel_launch(void* const* d_in, const int* in_sizes, int n_in,
                              void* d_out, int out_size, void* d_ws, size_t ws_size,
                              hipStream_t stream) {
  const int*   widx  = (const int*)d_in[0];
  const float* voice = (const float*)d_in[1];
  const int*   sent  = (const int*)d_in[2];
  const float* emb   = (const float*)d_in[4];
  const float* W1    = (const float*)d_in[5];
  const float* b1    = (const float*)d_in[6];
  const float* W2    = (const float*)d_in[7];
  const float* b2    = (const float*)d_in[8];
  float* out  = (float*)d_out;
  float* Aout = out + (size_t)BB * EE * SS * WW;  // O first, then A

  ushort* web  = (ushort*)d_ws;                   // [61440][300] bf16
  ushort* obf  = web + (size_t)18432000;          // [61440][300] bf16
  ushort* w2tp = obf + (size_t)18432000;          // [380 tiles][64 lanes][8] bf16

  hipLaunchKernelGGL(k_front, dim3(18127), dim3(256), 0, stream,
                     voice, sent, W1, b1, widx, emb, W2, Aout, web, w2tp);
  hipLaunchKernelGGL(k_pv, dim3(71, BB), dim3(256), 0, stream, Aout, web, sent, obf);
  hipLaunchKernelGGL(k_out2, dim3(960), dim3(256), 0, stream, obf, web, w2tp, b2, out);
}

// Round 4
// 125.577 us; speedup vs baseline: 1.2720x; 1.1437x over previous
//
#include <hip/hip_runtime.h>

#define BB 32
#define SS 64
#define WW 30
#define EE 300
#define VDD 128
#define HH 32

typedef short bf16x8 __attribute__((ext_vector_type(8)));
typedef float f32x4 __attribute__((ext_vector_type(4)));

__device__ __forceinline__ ushort f2bf(float f) {
  union { float f; unsigned u; } x; x.f = f;
  unsigned r = x.u + 0x7fffu + ((x.u >> 16) & 1u);
  return (ushort)(r >> 16);
}
__device__ __forceinline__ float bf2f(ushort u) {
  union { unsigned u; float f; } x; x.u = ((unsigned)u) << 16; return x.f;
}

// ---- K1: fused [qk (blocks 0..31)] [w2tp pack (32..126)] [gather (127..18126)] ----
__global__ __launch_bounds__(256) void k_front(
    const float* __restrict__ voice, const int* __restrict__ sent,
    const float* __restrict__ W1, const float* __restrict__ b1,
    const int* __restrict__ widx, const float* __restrict__ emb,
    const float* __restrict__ W2,
    float* __restrict__ Aout, ushort* __restrict__ web, ushort* __restrict__ w2tp) {
  __shared__ float sq[SS][33];
  int blk = blockIdx.x, t = threadIdx.x;
  if (blk < 32) {
    int b = blk;
    for (int o = t; o < SS * HH; o += 256) {
      int s = o >> 5, j = o & 31;
      const float* vrow = voice + ((size_t)b * SS + s) * VDD;
      float acc = b1[j];
      #pragma unroll 8
      for (int d = 0; d < VDD; ++d) acc += vrow[d] * W1[d * HH + j];
      sq[s][j] = acc;
    }
    __syncthreads();
    int sn = sent[b];
    int wv = t >> 6, ln = t & 63;
    for (int q = wv; q < SS; q += 4) {
      float acc = 0.f;
      #pragma unroll
      for (int j = 0; j < HH; ++j) acc += sq[q][j] * sq[ln][j];
      if (ln >= sn) acc -= 1e12f;
      float mx = acc;
      #pragma unroll
      for (int off = 32; off; off >>= 1) mx = fmaxf(mx, __shfl_xor(mx, off));
      float e = expf(acc - mx);
      float sm = e;
      #pragma unroll
      for (int off = 32; off; off >>= 1) sm += __shfl_xor(sm, off);
      Aout[((size_t)b * SS + q) * SS + ln] = e / sm;
    }
  } else if (blk < 127) {
    int g = (blk - 32) * 256 + t;
    if (g < 380 * 64) {
      int tI = g >> 6, lane = g & 63;
      int kc2 = tI / 19, ms = tI - kc2 * 19;
      int kc = kc2 >> 1, ks = kc2 & 1;
      int lg = lane >> 4, lr = lane & 15;
      int e = ms * 16 + lr;
      int kp0 = kc * 64 + ks * 32 + lg * 8;
      ushort v[8];
      #pragma unroll
      for (int j = 0; j < 8; ++j) {
        int kp = kp0 + j;
        int c = kp < 320 ? kp : kp - 20;
        bool ok = (e < EE) && (kp < 320 ? kp < 300 : kp < 620);
        v[j] = ok ? f2bf(W2[(size_t)c * EE + e]) : (ushort)0;
      }
      ushort* dst = w2tp + (size_t)g * 8;
      *(ushort4*)dst = *(ushort4*)&v[0];
      *(ushort4*)(dst + 4) = *(ushort4*)&v[4];
    }
  } else {
    int tid = (blk - 127) * 256 + t;
    if (tid < BB * SS * WW * 75) {
      int row = tid / 75, p = tid - row * 75;
      int idx = widx[row];
      float4 v = *(const float4*)(emb + (size_t)idx * EE + p * 4);
      ushort4 o;
      o.x = f2bf(v.x); o.y = f2bf(v.y); o.z = f2bf(v.z); o.w = f2bf(v.w);
      *(ushort4*)(web + (size_t)row * EE + p * 4) = o;
    }
  }
}

// ---- K2: Obf = mask .* (A @ V) via MFMA; vt = V^T staged w/ XOR k-group swizzle ----
__global__ __launch_bounds__(256) void k_pv2(
    const float* __restrict__ Aout, const ushort* __restrict__ web,
    const int* __restrict__ sent, ushort* __restrict__ obf) {
  __shared__ ushort sa[64][72];    // A bf16 [q][k]
  __shared__ ushort vt[256][72];   // V^T [n_local][k], k-group g stored at g^((n>>3)&7)
  int nc = blockIdx.x, b = blockIdx.y, t = threadIdx.x;
  int n0blk = nc * 256;
  // stage A (f32 -> bf16)
  for (int i = t; i < 64 * 16; i += 256) {
    int q = i >> 4, c4 = (i & 15) << 2;
    float4 f = *(const float4*)(Aout + (size_t)b * 4096 + q * 64 + c4);
    ushort4 u; u.x = f2bf(f.x); u.y = f2bf(f.y); u.z = f2bf(f.z); u.w = f2bf(f.w);
    *(ushort4*)&sa[q][c4] = u;
  }
  // stage V^T (web rows are [k][n] for this batch; view [2048][9000])
  int kk = t >> 5, nl0 = (t & 31) << 3;
  int swz = (t & 31) & 7;          // (n>>3)&7 is constant per thread
  for (int p = 0; p < 8; ++p) {
    int k = p * 8 + kk;
    int n = n0blk + nl0;
    ushort v[8];
    if (n + 7 < 9000) {
      const ushort* s = web + (size_t)(b * 64 + k) * 9000 + n;
      *(ushort4*)&v[0] = *(const ushort4*)s;
      *(ushort4*)&v[4] = *(const ushort4*)(s + 4);
    } else {
      #pragma unroll
      for (int j = 0; j < 8; ++j) v[j] = 0;
    }
    int c = (((k >> 3) ^ swz) << 3) + (k & 7);
    #pragma unroll
    for (int j = 0; j < 8; ++j) vt[nl0 + j][c] = v[j];
  }
  __syncthreads();
  int sn = sent[b];
  int wv = t >> 6, ln = t & 63, lr = ln & 15, lg = ln >> 4;
  int nbase = wv * 64;
  f32x4 acc[4][4];
  #pragma unroll
  for (int mt = 0; mt < 4; ++mt)
    #pragma unroll
    for (int nf = 0; nf < 4; ++nf) acc[mt][nf] = (f32x4){0.f, 0.f, 0.f, 0.f};
  #pragma unroll
  for (int ks = 0; ks < 2; ++ks) {
    if (ks * 32 < sn) {            // A columns >= sn are exactly 0 -> skip
      bf16x8 bfrag[4];
      #pragma unroll
      for (int nf = 0; nf < 4; ++nf) {
        int row = nbase + nf * 16 + lr;
        int gp = (ks * 4 + lg) ^ ((row >> 3) & 7);
        bfrag[nf] = *(const bf16x8*)&vt[row][gp << 3];
      }
      #pragma unroll
      for (int mt = 0; mt < 4; ++mt) {
        if (mt * 16 < sn) {
          bf16x8 afrag = *(const bf16x8*)&sa[mt * 16 + lr][ks * 32 + lg * 8];
          #pragma unroll
          for (int nf = 0; nf < 4; ++nf)
            acc[mt][nf] = __builtin_amdgcn_mfma_f32_16x16x32_bf16(
                afrag, bfrag[nf], acc[mt][nf], 0, 0, 0);
        }
      }
    }
  }
  #pragma unroll
  for (int mt = 0; mt < 4; ++mt) {
    #pragma unroll
    for (int nf = 0; nf < 4; ++nf) {
      int n = n0blk + nbase + nf * 16 + lr;
      if (n < 9000) {
        #pragma unroll
        for (int j = 0; j < 4; ++j) {
          int q = mt * 16 + lg * 4 + j;
          obf[(size_t)(b * 64 + q) * 9000 + n] =
              (q < sn) ? f2bf(acc[mt][nf][j]) : (ushort)0;
        }
      }
    }
  }
}

// ---- K3: out = (concat @ W2 + b2) computed transposed, pipelined ----
__global__ __launch_bounds__(256) void k_out2(
    const ushort* __restrict__ obf, const ushort* __restrict__ web,
    const ushort* __restrict__ w2tp, const float* __restrict__ b2,
    float* __restrict__ out) {
  __shared__ ushort sb[2][64][72];
  __shared__ float sb2[304];
  int blk = blockIdx.x, t = threadIdx.x;
  int wv = t >> 6, ln = t & 63;
  size_t r0 = (size_t)blk * 64;
  int bbat = blk / 30;
  int rin0 = (blk % 30) * 64;
  for (int i = t; i < 304; i += 256) sb2[i] = (i < 300) ? b2[i] : 0.f;
  f32x4 acc[5][4];
  #pragma unroll
  for (int i = 0; i < 5; ++i)
    #pragma unroll
    for (int nf = 0; nf < 4; ++nf) acc[i][nf] = (f32x4){0.f, 0.f, 0.f, 0.f};
  int rr = t >> 2, c0 = (t & 3) << 4;
  int lr = ln & 15, lg = ln >> 4;

  uint2 pr[4];
  auto LOADK = [&](int kc) {
    const ushort* src = (kc < 5) ? obf : web;
    int cb = (kc < 5 ? kc : kc - 5) * 64 + c0;
    const ushort* s = src + (r0 + rr) * 300 + cb;
    pr[0] = *(const uint2*)(s);
    pr[1] = *(const uint2*)(s + 4);
    pr[2] = *(const uint2*)(s + 8);
    pr[3] = *(const uint2*)(s + 12);
  };
  auto WRITEK = [&](int kc, int buf) {
    int cb = (kc < 5 ? kc : kc - 5) * 64 + c0;
    if (cb + 15 < 300) {
      *(uint2*)&sb[buf][rr][c0]      = pr[0];
      *(uint2*)&sb[buf][rr][c0 + 4]  = pr[1];
      *(uint2*)&sb[buf][rr][c0 + 8]  = pr[2];
      *(uint2*)&sb[buf][rr][c0 + 12] = pr[3];
    } else {
      union { uint2 u[4]; ushort s[16]; } tmp;
      tmp.u[0] = pr[0]; tmp.u[1] = pr[1]; tmp.u[2] = pr[2]; tmp.u[3] = pr[3];
      #pragma unroll
      for (int ii = 0; ii < 16; ++ii)
        sb[buf][rr][c0 + ii] = (cb + ii < 300) ? tmp.s[ii] : (ushort)0;
    }
  };

  LOADK(0);
  WRITEK(0, 0);
  __syncthreads();
  for (int kc = 0; kc < 10; ++kc) {
    int cur = kc & 1;
    if (kc < 9) LOADK(kc + 1);
    bf16x8 bfr[4][2];
    #pragma unroll
    for (int nf = 0; nf < 4; ++nf)
      #pragma unroll
      for (int ks = 0; ks < 2; ++ks)
        bfr[nf][ks] = *(const bf16x8*)&sb[cur][nf * 16 + lr][ks * 32 + lg * 8];
    #pragma unroll
    for (int i = 0; i < 5; ++i) {
      int ms = wv + 4 * i;
      if (ms < 19) {
        #pragma unroll
        for (int ks = 0; ks < 2; ++ks) {
          bf16x8 afr = *(const bf16x8*)(w2tp +
              ((size_t)((kc * 2 + ks) * 19 + ms) * 64 + ln) * 8);
          #pragma unroll
          for (int nf = 0; nf < 4; ++nf)
            acc[i][nf] = __builtin_amdgcn_mfma_f32_16x16x32_bf16(
                afr, bfr[nf][ks], acc[i][nf], 0, 0, 0);
        }
      }
    }
    if (kc < 9) WRITEK(kc + 1, cur ^ 1);
    __syncthreads();
  }
  #pragma unroll
  for (int i = 0; i < 5; ++i) {
    int ms = wv + 4 * i;
    if (ms >= 19) continue;
    #pragma unroll
    for (int nf = 0; nf < 4; ++nf) {
      int rin = rin0 + nf * 16 + lr;
      #pragma unroll
      for (int j = 0; j < 4; ++j) {
        int e = ms * 16 + lg * 4 + j;
        if (e < 300)
          out[(size_t)(bbat * 300 + e) * 1920 + rin] = acc[i][nf][j] + sb2[e];
      }
    }
  }
}

extern "C" void kernel_launch(void* const* d_in, const int* in_sizes, int n_in,
                              void* d_out, int out_size, void* d_ws, size_t ws_size,
                              hipStream_t stream) {
  const int*   widx  = (const int*)d_in[0];
  const float* voice = (const float*)d_in[1];
  const int*   sent  = (const int*)d_in[2];
  const float* emb   = (const float*)d_in[4];
  const float* W1    = (const float*)d_in[5];
  const float* b1    = (const float*)d_in[6];
  const float* W2    = (const float*)d_in[7];
  const float* b2    = (const float*)d_in[8];
  float* out  = (float*)d_out;
  float* Aout = out + (size_t)BB * EE * SS * WW;  // O first, then A

  ushort* web  = (ushort*)d_ws;                   // [61440][300] bf16
  ushort* obf  = web + (size_t)18432000;          // [61440][300] bf16
  ushort* w2tp = obf + (size_t)18432000;          // [380][64][8] bf16 fragment-major

  hipLaunchKernelGGL(k_front, dim3(18127), dim3(256), 0, stream,
                     voice, sent, W1, b1, widx, emb, W2, Aout, web, w2tp);
  hipLaunchKernelGGL(k_pv2, dim3(36, BB), dim3(256), 0, stream, Aout, web, sent, obf);
  hipLaunchKernelGGL(k_out2, dim3(960), dim3(256), 0, stream, obf, web, w2tp, b2, out);
}